// Round 10
// baseline (297.715 us; speedup 1.0000x reference)
//
#include <hip/hip_runtime.h>
#include <cstdint>
#include <cstddef>

constexpr int N = 50000;      // nodes
constexpr int D = 256;        // D_IN == D_OUT
constexpr int E = 400000;     // edges per relation
constexpr int R = 4;          // relations
constexpr int N4 = N * R;
constexpr int AROWS = 50048;  // 391 * 128, padded M
constexpr int ACOLS = 1024;   // 4 msg planes (loop plane lives in xh)
constexpr int KCAT = 1280;    // GEMM K = 4 msg planes + loop plane

constexpr int NBPR = 196;     // dst buckets per relation (ceil(N/256))
constexpr int NBKT = NBPR * R;        // 784
constexpr int BCAP = 2560;            // records per bucket (mean 2048, +11 sigma)
constexpr int MAXDEG = 32;            // LDS slots per node (P(Poi(8)>32) ~ 3e-12)
constexpr int ECHUNK = 4096;          // edges per partition block
constexpr int NCHUNKS = (E + ECHUNK - 1) / ECHUNK;  // 98
constexpr int MAXOVF = 4096;          // bucket-cap overflow list (never in practice)

typedef _Float16 f16x8 __attribute__((ext_vector_type(8)));
typedef float f32x4 __attribute__((ext_vector_type(4)));

__device__ __forceinline__ void load_lds16(const void* g, void* l) {
    __builtin_amdgcn_global_load_lds(
        (const __attribute__((address_space(1))) void*)g,
        (__attribute__((address_space(3))) void*)l, 16, 0, 0);
}

__device__ __forceinline__ float fast_tanh(float x) {
    const float xc = fminf(fmaxf(x, -9.0f), 9.0f);
    const float t = __builtin_amdgcn_exp2f(xc * 2.8853900817779268f);  // e^{2x}
    return (t - 1.0f) / (t + 1.0f);
}

// ---------------------------------------------------------------------------
// Stacked transposed weights: WT[c][k], k<1024 -> W_{k/256}[k%256][c],
// else loop_weight[k-1024][c]. fp16.
// ---------------------------------------------------------------------------
__global__ __launch_bounds__(256)
void wt_build_kernel(const float* __restrict__ w, const float* __restrict__ lw,
                     _Float16* __restrict__ wt) {
    const int i = blockIdx.x * blockDim.x + threadIdx.x;  // c*1280 + k
    if (i >= 256 * KCAT) return;
    const int c = i / KCAT;
    const int k = i - c * KCAT;
    const float v = (k < 1024) ? w[((k >> 8) << 16) + ((k & 255) << 8) + c]
                               : lw[((k - 1024) << 8) + c];
    wt[i] = (_Float16)v;
}

// ---------------------------------------------------------------------------
// x fp32 -> compact fp16 plane xh[N][256]
// ---------------------------------------------------------------------------
__global__ __launch_bounds__(256)
void convert_x_kernel(const float* __restrict__ x, _Float16* __restrict__ xh) {
    const long i = (long)blockIdx.x * blockDim.x + threadIdx.x;  // per 8 elems
    if (i >= (long)N * (D / 8)) return;
    const long n = i >> 5;
    const int c8 = (int)(i & 31) << 3;
    const float4* s = reinterpret_cast<const float4*>(x + n * D + c8);
    const float4 a = s[0], b = s[1];
    f16x8 v;
    v[0] = (_Float16)a.x; v[1] = (_Float16)a.y;
    v[2] = (_Float16)a.z; v[3] = (_Float16)a.w;
    v[4] = (_Float16)b.x; v[5] = (_Float16)b.y;
    v[6] = (_Float16)b.z; v[7] = (_Float16)b.w;
    *reinterpret_cast<f16x8*>(xh + n * D + c8) = v;
}

// ---------------------------------------------------------------------------
// Pass A: multisplit edges into 196 dst-range buckets per relation.
// ---------------------------------------------------------------------------
__global__ __launch_bounds__(256)
void partition_kernel(const int* __restrict__ edges, int* __restrict__ gcnt,
                      uint* __restrict__ buckets, int* __restrict__ ovf_n,
                      int2* __restrict__ ovf) {
    __shared__ int hist[256], base[256], run[256], gbase[256], ps[256];
    __shared__ int tot_s;
    __shared__ uint staging[ECHUNK];
    const int t = threadIdx.x;
    const int r = blockIdx.y;
    const int* srcp = edges + (size_t)r * 2 * E;
    const int* dstp = srcp + E;
    const int e0 = blockIdx.x * ECHUNK;

    hist[t] = 0;
    run[t] = 0;
    __syncthreads();

    uint rec[16];
#pragma unroll
    for (int u = 0; u < 16; ++u) {
        const int i = e0 + u * 256 + t;
        if (i < E) {
            rec[u] = ((uint)srcp[i] << 16) | (uint)dstp[i];
            atomicAdd(&hist[(rec[u] & 0xFFFFu) >> 8], 1);
        } else {
            rec[u] = 0xFFFFFFFFu;  // invalid marker (src=65535 impossible)
        }
    }
    __syncthreads();

    const int v = hist[t];
    ps[t] = v;
    __syncthreads();
    for (int off = 1; off < 256; off <<= 1) {
        const int x = (t >= off) ? ps[t - off] : 0;
        __syncthreads();
        ps[t] += x;
        __syncthreads();
    }
    base[t] = ps[t] - v;
    if (t == 255) tot_s = ps[255];
    if (v > 0) gbase[t] = atomicAdd(&gcnt[r * NBPR + t], v);
    __syncthreads();

#pragma unroll
    for (int u = 0; u < 16; ++u) {
        if (rec[u] != 0xFFFFFFFFu) {
            const int bl = (rec[u] & 0xFFFFu) >> 8;
            const int pos = base[bl] + atomicAdd(&run[bl], 1);
            staging[pos] = rec[u];
        }
    }
    __syncthreads();

    const int total = tot_s;
    for (int j = t; j < total; j += 256) {
        const uint rc = staging[j];
        const int bl = (rc & 0xFFFFu) >> 8;
        const int gp = gbase[bl] + (j - base[bl]);
        if (gp < BCAP) {
            buckets[(size_t)(r * NBPR + bl) * BCAP + gp] = rc;
        } else {  // statistically never (11 sigma); correctness fallback
            const int o = atomicAdd(ovf_n, 1);
            if (o < MAXOVF)
                ovf[o] = make_int2(r * N + (int)(rc & 0xFFFFu), (int)(rc >> 16));
        }
    }
}

// ---------------------------------------------------------------------------
// Pass B fused with gather: one block per (bucket, quarter) = 64 dst nodes.
// ---------------------------------------------------------------------------
__global__ __launch_bounds__(256)
void bucket_gather_kernel(const uint* __restrict__ buckets,
                          const int* __restrict__ gcnt,
                          const _Float16* __restrict__ xh,
                          const int2* __restrict__ ovf,
                          const int* __restrict__ ovf_n,
                          _Float16* __restrict__ A) {
    __shared__ int lcnt[64];
    __shared__ ushort lslots[64][MAXDEG];
    const int t = threadIdx.x;
    const int b = blockIdx.x >> 2;       // bucket 0..783
    const int quarter = blockIdx.x & 3;  // 64-node quarter
    const int r = b / NBPR;
    const int bl = b - r * NBPR;
    const int d0 = (bl << 8) + (quarter << 6);

    if (t < 64) lcnt[t] = 0;
    __syncthreads();

    const int nb = min(gcnt[b], BCAP);
    const uint* brec = buckets + (size_t)b * BCAP;
    for (int j = t; j < nb; j += 256) {
        const uint rc = brec[j];
        const int wi = (int)(rc & 0xFFFFu) - d0;
        if ((unsigned)wi < 64u) {
            const int pos = atomicAdd(&lcnt[wi], 1);
            if (pos < MAXDEG) lslots[wi][pos] = (ushort)(rc >> 16);
        }
    }
    __syncthreads();

    const int lane = t & 63;
    const int wv = t >> 6;           // wave 0..3 handles 16 nodes
    const int hf = lane >> 5;        // half-wave: even/odd edges
    const int lo8 = (lane & 31) * 8;
    const int on = min(*ovf_n, MAXOVF);

    for (int wi = wv * 16; wi < wv * 16 + 16; ++wi) {
        const int d = d0 + wi;
        if (d >= N) continue;
        const int m = lcnt[wi];
        float acc[8] = {};
        if (m <= MAXDEG) {
            for (int j = hf; j < m; j += 2) {
                const int s = lslots[wi][j];
                const f16x8 vv =
                    *reinterpret_cast<const f16x8*>(xh + (size_t)s * D + lo8);
#pragma unroll
                for (int k = 0; k < 8; ++k) acc[k] += (float)vv[k];
            }
        } else {  // slot overflow (never in practice): direct bucket scan
            for (int j = hf; j < nb; j += 2) {
                const uint rc = brec[j];
                if ((int)(rc & 0xFFFFu) == d) {
                    const f16x8 vv = *reinterpret_cast<const f16x8*>(
                        xh + (size_t)(rc >> 16) * D + lo8);
#pragma unroll
                    for (int k = 0; k < 8; ++k) acc[k] += (float)vv[k];
                }
            }
        }
        int ecnt = m;
        if (on > 0) {
            const int wfull = r * N + d;
            for (int o = 0; o < on; ++o) {
                const int2 e2 = ovf[o];
                if (e2.x == wfull) {
                    ecnt++;
                    if (hf == 0) {
                        const f16x8 vv = *reinterpret_cast<const f16x8*>(
                            xh + (size_t)e2.y * D + lo8);
#pragma unroll
                        for (int k = 0; k < 8; ++k) acc[k] += (float)vv[k];
                    }
                }
            }
        }
#pragma unroll
        for (int k = 0; k < 8; ++k) acc[k] += __shfl_xor(acc[k], 32);
        if (hf == 0) {
            const float rs = 1.0f / fmaxf((float)ecnt, 1.0f);
            f16x8 o8;
#pragma unroll
            for (int k = 0; k < 8; ++k) o8[k] = (_Float16)(acc[k] * rs);
            *reinterpret_cast<f16x8*>(A + (size_t)d * ACOLS + r * 256 + lo8) = o8;
        }
    }
}

// ---------------------------------------------------------------------------
// out[N,256] = tanh( [A | xh] @ WT^T + bias ), fp32 accum/out.
// BM=128, BN=64, BK=32, 4 waves (each 32 rows x 64 cols). DEPTH-3 pipeline,
// 4 LDS buffers, counted vmcnt (T4: never 0 in main loop):
//   step t: s_waitcnt vmcnt(6)  [tile t landed; t+1,t+2 in flight ACROSS
//           the barrier] ; s_barrier ; stage(t+3)->buf[(t+3)&3] (freed at
//           t-1, proven by this barrier) ; compute(t).
// Peeled tail: vmcnt(3), vmcnt(0). 3 global_load_lds per wave per stage
// (2 for A's 128 rows, 1 for B's 64 rows), wave w owns k-subtile plane w.
// Frag-read layout [4][rows][8] conflict-free ds_read_b128 (measured 0).
// ---------------------------------------------------------------------------
__global__ __launch_bounds__(256)
void gemm_final_kernel(const _Float16* __restrict__ A,
                       const _Float16* __restrict__ xh,
                       const _Float16* __restrict__ WT,
                       const float* __restrict__ bias, float* __restrict__ C) {
    __shared__ _Float16 As[4][4][128][8];  // [buf][plane][row][8]
    __shared__ _Float16 Bs[4][4][64][8];

    const int t = threadIdx.x;
    const int lane = t & 63;
    const int w = t >> 6;
    const long m0 = (long)blockIdx.x * 128;
    const int n0 = blockIdx.y * 64;

    const long ar0 = m0 + lane, ar1 = m0 + 64 + lane;
    const _Float16* Aa0 = A + ar0 * ACOLS + w * 8;
    const _Float16* Aa1 = A + ar1 * ACOLS + w * 8;
    const _Float16* Ax0 = xh + ar0 * D + w * 8;
    const _Float16* Ax1 = xh + ar1 * D + w * 8;
    const _Float16* Bg0 = WT + (long)(n0 + lane) * KCAT + w * 8;

    f32x4 acc[2][4];
#pragma unroll
    for (int i = 0; i < 2; ++i)
#pragma unroll
        for (int j = 0; j < 4; ++j) acc[i][j] = (f32x4){0.f, 0.f, 0.f, 0.f};

    const int kg = lane >> 4;
    const int rr = lane & 15;
    constexpr int NT = KCAT / 32;  // 40

    auto stage = [&](int kt, int buf) {
        const int k0 = kt * 32;
        _Float16* a0 = &As[buf][w][0][0];
        _Float16* a1 = &As[buf][w][64][0];
        _Float16* b0 = &Bs[buf][w][0][0];
        if (k0 < ACOLS) {
            load_lds16(Aa0 + k0, a0);
            load_lds16(Aa1 + k0, a1);
        } else {
            load_lds16(Ax0 + (k0 - ACOLS), a0);
            load_lds16(Ax1 + (k0 - ACOLS), a1);
        }
        load_lds16(Bg0 + k0, b0);
    };

    auto compute = [&](int buf) {
        f16x8 af[2], bf[4];
#pragma unroll
        for (int f = 0; f < 2; ++f)
            af[f] = *reinterpret_cast<const f16x8*>(
                &As[buf][kg][w * 32 + f * 16 + rr][0]);
#pragma unroll
        for (int g = 0; g < 4; ++g)
            bf[g] = *reinterpret_cast<const f16x8*>(&Bs[buf][kg][g * 16 + rr][0]);
        __builtin_amdgcn_s_setprio(1);
#pragma unroll
        for (int i = 0; i < 2; ++i)
#pragma unroll
            for (int j = 0; j < 4; ++j)
                acc[i][j] = __builtin_amdgcn_mfma_f32_16x16x32_f16(
                    af[i], bf[j], acc[i][j], 0, 0, 0);
        __builtin_amdgcn_s_setprio(0);
    };

    // prologue: stage tiles 0,1,2 (9 loads in flight)
    stage(0, 0);
    stage(1, 1);
    stage(2, 2);

#pragma unroll 4
    for (int kt = 0; kt < NT - 2; ++kt) {
        asm volatile("s_waitcnt vmcnt(6)" ::: "memory");  // tile kt landed
        __builtin_amdgcn_sched_barrier(0);
        __builtin_amdgcn_s_barrier();  // all waves: tile kt landed; buf (kt+3)&3 free
        __builtin_amdgcn_sched_barrier(0);
        if (kt + 3 < NT) stage(kt + 3, (kt + 3) & 3);
        compute(kt & 3);
    }
    // kt = NT-2: only tiles NT-2, NT-1 outstanding (6 loads)
    asm volatile("s_waitcnt vmcnt(3)" ::: "memory");
    __builtin_amdgcn_sched_barrier(0);
    __builtin_amdgcn_s_barrier();
    __builtin_amdgcn_sched_barrier(0);
    compute((NT - 2) & 3);
    // kt = NT-1
    asm volatile("s_waitcnt vmcnt(0)" ::: "memory");
    __builtin_amdgcn_sched_barrier(0);
    __builtin_amdgcn_s_barrier();
    __builtin_amdgcn_sched_barrier(0);
    compute((NT - 1) & 3);

    // epilogue: C/D map col=lane&15, row=(lane>>4)*4+reg
    const int crow0 = (lane >> 4) * 4;
    const int ccol = lane & 15;
#pragma unroll
    for (int i = 0; i < 2; ++i) {
        const long row = m0 + w * 32 + i * 16 + crow0;
#pragma unroll
        for (int j = 0; j < 4; ++j) {
            const int col = n0 + j * 16 + ccol;
            const float b = bias[col];
#pragma unroll
            for (int q = 0; q < 4; ++q) {
                const long rgl = row + q;
                if (rgl < N) C[rgl * 256 + col] = fast_tanh(acc[i][j][q] + b);
            }
        }
    }
}

// ---------------------------------------------------------------------------
extern "C" void kernel_launch(void* const* d_in, const int* in_sizes, int n_in,
                              void* d_out, int out_size, void* d_ws, size_t ws_size,
                              hipStream_t stream) {
    const float* x           = (const float*)d_in[0];
    const int*   edges       = (const int*)d_in[1];   // [4][2][400000] int32
    const float* weight      = (const float*)d_in[2]; // [4][256][256]
    const float* loop_weight = (const float*)d_in[3]; // [256][256]
    const float* h_bias      = (const float*)d_in[4]; // [256]
    float*       out         = (float*)d_out;
    (void)in_sizes; (void)n_in; (void)out_size; (void)ws_size;

    size_t off = 0;
    auto carve = [&](size_t bytes) -> void* {
        void* p = (char*)d_ws + off;
        off = (off + bytes + 255) & ~(size_t)255;
        return p;
    };

    _Float16* A     = (_Float16*)carve((size_t)AROWS * ACOLS * sizeof(_Float16));
    _Float16* xh    = (_Float16*)carve((size_t)AROWS * D * sizeof(_Float16));
    _Float16* WT    = (_Float16*)carve((size_t)KCAT * 256 * sizeof(_Float16));
    int*      gcnt  = (int*)carve((size_t)NBKT * sizeof(int));
    int*      ovf_n = (int*)carve(256);
    int2*     ovf   = (int2*)carve((size_t)MAXOVF * sizeof(int2));
    // bucket array (8 MB) aliases d_out: dead before gemm_final overwrites it.
    uint* buckets = (uint*)d_out;  // NBKT*BCAP*4 = 8.03 MB <= 51.2 MB

    hipMemsetAsync(gcnt, 0, (size_t)NBKT * sizeof(int), stream);
    hipMemsetAsync(ovf_n, 0, sizeof(int), stream);

    wt_build_kernel<<<(256 * KCAT + 255) / 256, 256, 0, stream>>>(weight, loop_weight, WT);
    convert_x_kernel<<<(N * (D / 8) + 255) / 256, 256, 0, stream>>>(x, xh);

    // multisplit edges -> dst-range buckets
    partition_kernel<<<dim3(NCHUNKS, R), 256, 0, stream>>>(edges, gcnt, buckets,
                                                           ovf_n, ovf);
    // LDS slot build + gather fused; writes msg planes into A
    bucket_gather_kernel<<<NBKT * 4, 256, 0, stream>>>(buckets, gcnt, xh,
                                                       ovf, ovf_n, A);
    // out = tanh([A | xh] @ Wcat + bias)
    gemm_final_kernel<<<dim3(AROWS / 128, 4), 256, 0, stream>>>(A, xh, WT, h_bias, out);
}